// Round 7
// baseline (278.962 us; speedup 1.0000x reference)
//
#include <hip/hip_runtime.h>

#define NN 100000
#define NP 100096          // multiple of 32/64
#define NT (NP / 32)       // 3128 gemm tiles
#define EE 600000
#define GG 512
#define LN_EPS 1e-5f

typedef __attribute__((ext_vector_type(8))) __bf16 bf16x8;
typedef __attribute__((ext_vector_type(4))) float f32x4;

__device__ __forceinline__ unsigned short f2bf(float f) {
    unsigned int u = __float_as_uint(f);
    u = (u + 0x7fffu + ((u >> 16) & 1u)) >> 16;
    return (unsigned short)u;
}
__device__ __forceinline__ unsigned int pack2(float a, float b) {
    return (unsigned int)f2bf(a) | ((unsigned int)f2bf(b) << 16);
}
__device__ __forceinline__ void acc8(float* s, uint4 v) {
    s[0] += __uint_as_float(v.x << 16);
    s[1] += __uint_as_float(v.x & 0xffff0000u);
    s[2] += __uint_as_float(v.y << 16);
    s[3] += __uint_as_float(v.y & 0xffff0000u);
    s[4] += __uint_as_float(v.z << 16);
    s[5] += __uint_as_float(v.z & 0xffff0000u);
    s[6] += __uint_as_float(v.w << 16);
    s[7] += __uint_as_float(v.w & 0xffff0000u);
}

// ---------------- merged prep: H0r + weight prep + XCD-partitioned degree count --------
// Edge atomics are XCD-partitioned (R6): block group x=eb%8 lands on XCD x
// (round-robin dispatch heuristic) and only touches deg[d] for
// d in [x*12500,(x+1)*12500) -> atomic lines stay XCD-local, no cross-XCD
// migration. Costs 8x sequential re-read of the dst array (19 MB, cheap).
#define PREP_A (NP * 10)
#define PREP_W0 (128 * 160)
#define PREP_W1 (128 * 256)
#define PREP_WF (50 * 256 + 50 * 50 + 50 * 10)   // transposed MLP weights (15800)
#define PREP_AB   (PREP_A / 256)                 // 3910 blocks
#define PREP_W0B  (PREP_W0 / 256)                // 80
#define PREP_W1B  (PREP_W1 / 256)                // 128
#define PREP_WFB  ((PREP_WF + 255) / 256)        // 62 blocks (padded)
#define PREP_FIXED_B (PREP_AB + PREP_W0B + PREP_W1B + PREP_WFB)
#define ECHUNK 2048
#define NCHUNK ((EE + ECHUNK - 1) / ECHUNK)      // 293
#define PREP_GRID (PREP_FIXED_B + NCHUNK * 8)
#define PART 12500                               // 8*12500 = 100000 = NN

__global__ __launch_bounds__(256) void prep_kernel(
    const float* __restrict__ x, const float* __restrict__ xdims,
    const int* __restrict__ stt, const float* __restrict__ emb,
    const int* __restrict__ ei,
    const float* __restrict__ Wl0, const float* __restrict__ Wr0,
    const float* __restrict__ Wl1, const float* __restrict__ Wr1,
    const float* __restrict__ Wf0, const float* __restrict__ Wf1,
    const float* __restrict__ Wf2,
    unsigned short* __restrict__ H0r,
    unsigned short* __restrict__ Wt0, unsigned short* __restrict__ Wt1,
    float* __restrict__ W0T, float* __restrict__ W1T, float* __restrict__ W2T,
    int* __restrict__ deg)
{
    int blk = blockIdx.x;
    if (blk >= PREP_FIXED_B) {
        // ---- XCD-partitioned degree count ----
        int eb = blk - PREP_FIXED_B;
        int px = eb & 7, c = eb >> 3;
        int lo = px * PART, hi = lo + PART;
        int base = c * ECHUNK + threadIdx.x * 8;
        int d[8]; int n = 0;
        if (base + 8 <= EE) {
            int4 a = *(const int4*)&ei[EE + base];
            int4 b = *(const int4*)&ei[EE + base + 4];
            d[0]=a.x; d[1]=a.y; d[2]=a.z; d[3]=a.w;
            d[4]=b.x; d[5]=b.y; d[6]=b.z; d[7]=b.w;
            n = 8;
        } else {
            for (int u = 0; u < 8 && base + u < EE; ++u) d[u] = ei[EE + base + u];
            n = (base < EE) ? (EE - base < 8 ? EE - base : 8) : 0;
        }
        for (int u = 0; u < n; ++u)
            if (d[u] >= lo && d[u] < hi) atomicAdd(&deg[d[u]], 1);
        return;
    }
    int idx = blk * 256 + threadIdx.x;
    if (idx < PREP_A) {
        int node = idx / 10;
        int c8 = (idx - node * 10) * 8;   // feature base 0..72
        unsigned short vals[8];
        if (node < NN) {
            int st = stt[node];
            #pragma unroll
            for (int i = 0; i < 8; ++i) {
                int f = c8 + i;
                float v = 0.f;
                if (f < 60)      v = x[node * 60 + f];
                else if (f < 62) v = xdims[node * 2 + (f - 60)];
                else if (f < 74) v = emb[st * 12 + (f - 62)];
                vals[i] = f2bf(v);
            }
        } else {
            #pragma unroll
            for (int i = 0; i < 8; ++i) vals[i] = 0;
        }
        uint4 o;
        o.x = (unsigned)vals[0] | ((unsigned)vals[1] << 16);
        o.y = (unsigned)vals[2] | ((unsigned)vals[3] << 16);
        o.z = (unsigned)vals[4] | ((unsigned)vals[5] << 16);
        o.w = (unsigned)vals[6] | ((unsigned)vals[7] << 16);
        *(uint4*)(H0r + (size_t)node * 80 + c8) = o;
    } else if (idx < PREP_A + PREP_W0) {
        int j = idx - PREP_A;
        int n = j / 160, k = j - n * 160;
        float v = 0.f;
        if (k < 74)                  v = Wl0[k * 128 + n];
        else if (k >= 80 && k < 154) v = Wr0[(k - 80) * 128 + n];
        Wt0[(size_t)n * 160 + k] = f2bf(v);
    } else if (idx < PREP_A + PREP_W0 + PREP_W1) {
        int j = idx - PREP_A - PREP_W0;
        int n = j >> 8, k = j & 255;
        float v = (k < 128) ? Wl1[k * 128 + n] : Wr1[(k - 128) * 128 + n];
        Wt1[(size_t)n * 256 + k] = f2bf(v);
    } else {
        int j = idx - PREP_A - PREP_W0 - PREP_W1;
        if (j < 50 * 256) {
            int t = j >> 8, k = j & 255;
            W0T[t * 256 + k] = Wf0[k * 50 + t];
        } else if (j < 50 * 256 + 50 * 50) {
            int q = j - 50 * 256; int t = q / 50, k = q - t * 50;
            W1T[t * 50 + k] = Wf1[k * 50 + t];
        } else if (j < PREP_WF) {
            int q = j - 50 * 256 - 50 * 50; int t = q / 50, k = q - t * 50;
            W2T[t * 50 + k] = Wf2[k * 10 + t];
        }
    }
}

// ---------------- exclusive scan of deg -> offs (local) + bsum ----------------
__global__ __launch_bounds__(256) void scan1_kernel(
    const int* __restrict__ deg, int* __restrict__ offs, int* __restrict__ bsum)
{
    __shared__ int ts[256];
    int t = threadIdx.x;
    int base = blockIdx.x * 2048 + t * 8;
    int d[8];
    if (base + 8 <= NN) {
        int4 a = *(const int4*)&deg[base];
        int4 b = *(const int4*)&deg[base + 4];
        d[0]=a.x; d[1]=a.y; d[2]=a.z; d[3]=a.w;
        d[4]=b.x; d[5]=b.y; d[6]=b.z; d[7]=b.w;
    } else {
        #pragma unroll
        for (int i = 0; i < 8; ++i) d[i] = (base + i < NN) ? deg[base + i] : 0;
    }
    int e[8]; int run = 0;
    #pragma unroll
    for (int i = 0; i < 8; ++i) { e[i] = run; run += d[i]; }
    ts[t] = run;
    int tot = run;
    __syncthreads();
    for (int off = 1; off < 256; off <<= 1) {
        int u = (t >= off) ? ts[t - off] : 0;
        __syncthreads();
        ts[t] += u;
        __syncthreads();
    }
    int pre = ts[t] - tot;
    #pragma unroll
    for (int i = 0; i < 8; ++i) if (base + i < NN) offs[base + i] = e[i] + pre;
    if (t == 255) bsum[blockIdx.x] = ts[255];
}

__global__ void scan2_kernel(int* __restrict__ bsum, int nb)
{
    int t = threadIdx.x;   // one wave
    int v = (t < nb) ? bsum[t] : 0;
    int inc = v;
    for (int off = 1; off < 64; off <<= 1) {
        int u = __shfl_up(inc, off, 64);
        if (t >= off) inc += u;
    }
    if (t < nb) bsum[t] = inc - v;   // exclusive
}

// ---------------- CSR fill, XCD-partitioned (R6) ----------------
// Same chunk x partition structure as prep's deg section: cur[] atomics and
// csr[] writes (dst-sorted -> contiguous region per partition) stay XCD-local.
__global__ __launch_bounds__(256) void fill_csr_kernel(
    const int* __restrict__ ei, int* __restrict__ cur,
    const int* __restrict__ offs, const int* __restrict__ bsum,
    int* __restrict__ csr)
{
    int px = blockIdx.x & 7, c = blockIdx.x >> 3;
    int lo = px * PART, hi = lo + PART;
    int base = c * ECHUNK + threadIdx.x * 8;
    int d[8]; int n = 0;
    if (base + 8 <= EE) {
        int4 a = *(const int4*)&ei[EE + base];
        int4 b = *(const int4*)&ei[EE + base + 4];
        d[0]=a.x; d[1]=a.y; d[2]=a.z; d[3]=a.w;
        d[4]=b.x; d[5]=b.y; d[6]=b.z; d[7]=b.w;
        n = 8;
    } else {
        for (int u = 0; u < 8 && base + u < EE; ++u) d[u] = ei[EE + base + u];
        n = (base < EE) ? (EE - base < 8 ? EE - base : 8) : 0;
    }
    for (int u = 0; u < n; ++u) {
        int dd = d[u];
        if (dd >= lo && dd < hi) {
            int p = offs[dd] + bsum[dd >> 11] + atomicAdd(&cur[dd], 1);
            csr[p] = ei[base + u];
        }
    }
}

// ---------------- fused gather-agg + GEMM (+ LN + ReLU; POOL: + pooling) ----------
// block = 256 thr = 4 waves; 32 nodes x 128 cols per block.  (Frozen R5/R1 form:
// R1/R3/R4 proved gather time invariant to ILP width, occupancy, and wave
// count — runs at the random-line fabric wall, FETCH/dur = 1.34 TB/s.)
// A staged in LDS stride AS=K+8; A-frag per m120; C/D per m89.
// Ledger: regB-resident, persistent, direct-global A-frags, async
// global_load_lds, 64-node tile, 2-tile dbuf, 8-wide clamped gather (R1),
// 8-wave/512-thr (R4) ALL null-or-regress vs this form.
template<int K, bool POOL>
__global__ __launch_bounds__(256, 4) void gemm_kernel(
    const unsigned short* __restrict__ Hr,        // gather + root source (dense K/2 cols)
    const unsigned short* __restrict__ Wt,
    const float* __restrict__ bias, const float* __restrict__ gamma,
    const float* __restrict__ beta,
    unsigned short* __restrict__ outH,            // !POOL: H1 (dense 128)
    const int* __restrict__ batch,                // POOL only
    float* __restrict__ psum, int* __restrict__ pmax, int* __restrict__ gcnt,
    const int* __restrict__ csr, const int* __restrict__ offs,
    const int* __restrict__ bsum, const int* __restrict__ deg)
{
    constexpr int KT = K / 32, AS = K + 8, KH = K / 2, CH = KH / 8;
    constexpr int SMEM = (32 * AS * 2 > 32 * 128 * 4) ? 32 * AS * 2 : 32 * 128 * 4;
    __shared__ __align__(16) char smem[SMEM];     // Asm; aliased by Hs post-MFMA (POOL)
    unsigned short* Asm = (unsigned short*)smem;
    float* Hs = (float*)smem;
    __shared__ __align__(16) float sP[32 * 4];
    __shared__ __align__(16) float qP[32 * 4];
    __shared__ int bS[POOL ? 32 : 1];

    const int tid = threadIdx.x;
    const int n0 = blockIdx.x * 32;
    const int l = tid & 63, w = tid >> 6;
    const int fg = l >> 4, c0 = l & 15;

    if (POOL && tid < 32) {
        int gn = n0 + tid;
        bS[tid] = (gn < NN) ? batch[gn] : -1;
    }
    float bia[2], gam[2], bet[2];
    #pragma unroll
    for (int j = 0; j < 2; ++j) {
        int col = (2 * w + j) * 16 + c0;
        bia[j] = bias[col]; gam[j] = gamma[col]; bet[j] = beta[col];
    }
    const unsigned short* bp0 = Wt + (size_t)((2 * w + 0) * 16 + c0) * K + fg * 8;
    const unsigned short* bp1 = Wt + (size_t)((2 * w + 1) * 16 + c0) * K + fg * 8;

    // ---- fused staging: Asm row = [neighbor-mean (KH) | root (KH)] ----
    {
        const int ln = tid & 15, nl = tid >> 4;   // 16 lanes per node, 16 nodes/pass
        #pragma unroll
        for (int half = 0; half < 2; ++half) {
            int node = half * 16 + nl;
            int gn = n0 + node;
            if (ln < CH) {
                uint4 rv = *(const uint4*)(Hr + (size_t)gn * KH + ln * 8);
                int d = 0, st = 0;
                if (gn < NN) { d = deg[gn]; st = offs[gn] + bsum[gn >> 11]; }
                float iv = 1.0f / (float)(d > 1 ? d : 1);
                float s[8];
                #pragma unroll
                for (int i = 0; i < 8; ++i) s[i] = 0.f;
                int e = 0;
                for (; e + 4 <= d; e += 4) {
                    int i0 = csr[st + e],     i1 = csr[st + e + 1];
                    int i2 = csr[st + e + 2], i3 = csr[st + e + 3];
                    uint4 v0 = *(const uint4*)(Hr + (size_t)i0 * KH + ln * 8);
                    uint4 v1 = *(const uint4*)(Hr + (size_t)i1 * KH + ln * 8);
                    uint4 v2 = *(const uint4*)(Hr + (size_t)i2 * KH + ln * 8);
                    uint4 v3 = *(const uint4*)(Hr + (size_t)i3 * KH + ln * 8);
                    acc8(s, v0); acc8(s, v1); acc8(s, v2); acc8(s, v3);
                }
                for (; e < d; ++e) {
                    int i0 = csr[st + e];
                    uint4 v0 = *(const uint4*)(Hr + (size_t)i0 * KH + ln * 8);
                    acc8(s, v0);
                }
                uint4 o;
                o.x = pack2(s[0] * iv, s[1] * iv);
                o.y = pack2(s[2] * iv, s[3] * iv);
                o.z = pack2(s[4] * iv, s[5] * iv);
                o.w = pack2(s[6] * iv, s[7] * iv);
                *(uint4*)(Asm + node * AS + ln * 8) = o;            // agg half
                *(uint4*)(Asm + node * AS + KH + ln * 8) = rv;      // root half
            }
        }
    }

    const unsigned short* ar0 = Asm + (0 * 16 + c0) * AS + fg * 8;
    const unsigned short* ar1 = Asm + (1 * 16 + c0) * AS + fg * 8;
    __syncthreads();

    f32x4 acc[2][2];
    acc[0][0] = (f32x4){0.f,0.f,0.f,0.f}; acc[0][1] = (f32x4){0.f,0.f,0.f,0.f};
    acc[1][0] = (f32x4){0.f,0.f,0.f,0.f}; acc[1][1] = (f32x4){0.f,0.f,0.f,0.f};

    #pragma unroll
    for (int kt = 0; kt < KT; ++kt) {
        bf16x8 b0 = *(const bf16x8*)(bp0 + kt * 32);
        bf16x8 b1 = *(const bf16x8*)(bp1 + kt * 32);
        bf16x8 a0 = *(const bf16x8*)(ar0 + kt * 32);
        bf16x8 a1 = *(const bf16x8*)(ar1 + kt * 32);
        acc[0][0] = __builtin_amdgcn_mfma_f32_16x16x32_bf16(a0, b0, acc[0][0], 0, 0, 0);
        acc[0][1] = __builtin_amdgcn_mfma_f32_16x16x32_bf16(a0, b1, acc[0][1], 0, 0, 0);
        acc[1][0] = __builtin_amdgcn_mfma_f32_16x16x32_bf16(a1, b0, acc[1][0], 0, 0, 0);
        acc[1][1] = __builtin_amdgcn_mfma_f32_16x16x32_bf16(a1, b1, acc[1][1], 0, 0, 0);
    }

    // LN phase 1: per-wave partials over this wave's 32 cols
    #pragma unroll
    for (int m = 0; m < 2; ++m) {
        #pragma unroll
        for (int r = 0; r < 4; ++r) {
            float h0v = acc[m][0][r] + bia[0];
            float h1v = acc[m][1][r] + bia[1];
            float s = h0v + h1v, q = h0v * h0v + h1v * h1v;
            #pragma unroll
            for (int mm = 1; mm < 16; mm <<= 1) {
                s += __shfl_xor(s, mm, 64);
                q += __shfl_xor(q, mm, 64);
            }
            if (c0 == 0) {
                int node = m * 16 + fg * 4 + r;
                sP[node * 4 + w] = s;
                qP[node * 4 + w] = q;
            }
        }
    }
    __syncthreads();   // MFMA Asm reads done; sP/qP visible

    // LN phase 2 + ReLU + store
    #pragma unroll
    for (int m = 0; m < 2; ++m) {
        #pragma unroll
        for (int r = 0; r < 4; ++r) {
            int node = m * 16 + fg * 4 + r;
            float4 sv = *(const float4*)&sP[node * 4];
            float4 qv = *(const float4*)&qP[node * 4];
            float s = (sv.x + sv.y) + (sv.z + sv.w);
            float q = (qv.x + qv.y) + (qv.z + qv.w);
            float mu   = s * (1.f / 128.f);
            float var  = q * (1.f / 128.f) - mu * mu;
            float rinv = rsqrtf(var + LN_EPS);
            float h0v = acc[m][0][r] + bia[0];
            float h1v = acc[m][1][r] + bia[1];
            float v0 = fmaxf(0.f, (h0v - mu) * rinv * gam[0] + bet[0]);
            float v1 = fmaxf(0.f, (h1v - mu) * rinv * gam[1] + bet[1]);
            if (POOL) {
                Hs[node * 128 + (2 * w) * 16 + c0]     = v0;
                Hs[node * 128 + (2 * w + 1) * 16 + c0] = v1;
            } else {
                size_t gn = (size_t)(n0 + node);
                float keep = (gn < (size_t)NN) ? 1.f : 0.f;
                outH[gn * 128 + (2 * w) * 16 + c0]     = f2bf(v0 * keep);
                outH[gn * 128 + (2 * w + 1) * 16 + c0] = f2bf(v1 * keep);
            }
        }
    }
    if (!POOL) return;
    __syncthreads();

    // fused pooling: 128 threads, one column each; sorted batch -> few flushes.
    // Thread j==0 also accumulates per-graph node counts.
    if (tid < 128) {
        int j = tid;
        int curg = -1; float s = 0.f, m = 0.f; int rl = 0;
        #pragma unroll 4
        for (int n = 0; n < 32; ++n) {
            int gb = bS[n];
            if (gb < 0) break;
            if (gb != curg) {
                if (curg >= 0) {
                    atomicAdd(&psum[curg * 128 + j], s);
                    atomicMax(&pmax[curg * 128 + j], __float_as_int(m));
                    if (j == 0) atomicAdd(&gcnt[curg], rl);
                }
                curg = gb; s = 0.f; m = 0.f; rl = 0;
            }
            float v = Hs[n * 128 + j];
            s += v; m = fmaxf(m, v);
            rl += 1;
        }
        if (curg >= 0) {
            atomicAdd(&psum[curg * 128 + j], s);
            atomicMax(&pmax[curg * 128 + j], __float_as_int(m));
            if (j == 0) atomicAdd(&gcnt[curg], rl);
        }
    }
}

// ---------------- final MLP (transposed weights: thread t streams a contiguous row) ----
__global__ __launch_bounds__(64) void mlp_kernel(
    const float* __restrict__ psum, const int* __restrict__ pmax,
    const int* __restrict__ gcnt,
    const float* __restrict__ W0T, const float* __restrict__ bf0,
    const float* __restrict__ W1T, const float* __restrict__ bf1,
    const float* __restrict__ W2T, const float* __restrict__ bf2,
    float* __restrict__ out)
{
    __shared__ float z[256];
    __shared__ float t1[50];
    __shared__ float t2[50];
    int g = blockIdx.x, t = threadIdx.x;
    int c = gcnt[g];
    float ic = 1.0f / (float)(c > 1 ? c : 1);
    for (int j = t; j < 128; j += 64) {
        z[j]       = psum[g * 128 + j] * ic;
        z[128 + j] = __int_as_float(pmax[g * 128 + j]);
    }
    __syncthreads();
    if (t < 50) {
        const float* wr = W0T + t * 256;
        float a0 = bf0[t], a1 = 0.f, a2 = 0.f, a3 = 0.f;
        for (int k = 0; k < 256; k += 4) {
            float4 wv = *(const float4*)(wr + k);
            a0 = fmaf(z[k],     wv.x, a0);
            a1 = fmaf(z[k + 1], wv.y, a1);
            a2 = fmaf(z[k + 2], wv.z, a2);
            a3 = fmaf(z[k + 3], wv.w, a3);
        }
        t1[t] = fmaxf((a0 + a1) + (a2 + a3), 0.0f);
    }
    __syncthreads();
    if (t < 50) {
        const float* wr = W1T + t * 50;
        float a0 = bf1[t], a1 = 0.f;
        for (int k = 0; k < 50; k += 2) {
            a0 = fmaf(t1[k],     wr[k],     a0);
            a1 = fmaf(t1[k + 1], wr[k + 1], a1);
        }
        t2[t] = fmaxf(a0 + a1, 0.0f);
    }
    __syncthreads();
    if (t < 10) {
        const float* wr = W2T + t * 50;
        float a0 = bf2[t], a1 = 0.f;
        for (int k = 0; k < 50; k += 2) {
            a0 = fmaf(t2[k],     wr[k],     a0);
            a1 = fmaf(t2[k + 1], wr[k + 1], a1);
        }
        out[g * 10 + t] = fmaxf(a0 + a1, 0.0f);
    }
}

// ---------------- launcher ----------------
extern "C" void kernel_launch(void* const* d_in, const int* in_sizes, int n_in,
                              void* d_out, int out_size, void* d_ws, size_t ws_size,
                              hipStream_t stream)
{
    const float* x     = (const float*)d_in[0];
    const float* xdims = (const float*)d_in[1];
    const int*   stt   = (const int*)d_in[2];
    const int*   ei    = (const int*)d_in[3];
    const int*   batch = (const int*)d_in[4];
    const float* emb   = (const float*)d_in[5];
    const float* Wl0   = (const float*)d_in[6];
    const float* bl0   = (const float*)d_in[7];
    const float* Wr0   = (const float*)d_in[8];
    const float* g0    = (const float*)d_in[9];
    const float* bn0   = (const float*)d_in[10];
    const float* Wl1   = (const float*)d_in[11];
    const float* bl1   = (const float*)d_in[12];
    const float* Wr1   = (const float*)d_in[13];
    const float* g1    = (const float*)d_in[14];
    const float* bn1   = (const float*)d_in[15];
    const float* Wf0   = (const float*)d_in[16];
    const float* bf0   = (const float*)d_in[17];
    const float* Wf1   = (const float*)d_in[18];
    const float* bf1   = (const float*)d_in[19];
    const float* Wf2   = (const float*)d_in[20];
    const float* bf2   = (const float*)d_in[21];

    char* w = (char*)d_ws;
    unsigned short* H0r = (unsigned short*)w; w += (size_t)NP * 80 * 2;
    unsigned short* H1  = (unsigned short*)w; w += (size_t)NP * 128 * 2;
    unsigned short* Wt0 = (unsigned short*)w; w += (size_t)128 * 160 * 2;
    unsigned short* Wt1 = (unsigned short*)w; w += (size_t)128 * 256 * 2;
    float* W0T = (float*)w; w += (size_t)50 * 256 * 4;
    float* W1T = (float*)w; w += (size_t)50 * 50 * 4;
    float* W2T = (float*)w; w += (size_t)10 * 50 * 4;
    int*   csr    = (int*)w;   w += (size_t)EE * 4;
    int*   offs   = (int*)w;   w += (size_t)NN * 4;
    int*   bsum   = (int*)w;   w += 1024;
    // zeroed region (one memset):
    char* zbeg = w;
    int*   deg  = (int*)w;   w += (size_t)NP * 4;
    int*   cur  = (int*)w;   w += (size_t)NN * 4;
    float* psum = (float*)w; w += (size_t)GG * 128 * 4;
    int*   pmax = (int*)w;   w += (size_t)GG * 128 * 4;
    int*   gcnt = (int*)w;   w += (size_t)GG * 4;
    size_t zsz = (size_t)(w - zbeg);

    hipMemsetAsync(zbeg, 0, zsz, stream);

    prep_kernel<<<PREP_GRID, 256, 0, stream>>>(
        x, xdims, stt, emb, ei, Wl0, Wr0, Wl1, Wr1, Wf0, Wf1, Wf2,
        H0r, Wt0, Wt1, W0T, W1T, W2T, deg);

    int nb = (NN + 2047) / 2048;   // 49
    scan1_kernel<<<nb, 256, 0, stream>>>(deg, offs, bsum);
    scan2_kernel<<<1, 64, 0, stream>>>(bsum, nb);
    fill_csr_kernel<<<NCHUNK * 8, 256, 0, stream>>>(ei, cur, offs, bsum, csr);

    gemm_kernel<160, false><<<NT, 256, 0, stream>>>(
        H0r, Wt0, bl0, g0, bn0, H1, nullptr, nullptr, nullptr, nullptr,
        csr, offs, bsum, deg);
    gemm_kernel<256, true><<<NT, 256, 0, stream>>>(
        H1, Wt1, bl1, g1, bn1, nullptr, batch, psum, pmax, gcnt,
        csr, offs, bsum, deg);

    mlp_kernel<<<GG, 64, 0, stream>>>(psum, pmax, gcnt, W0T, bf0, W1T, bf1, W2T, bf2,
                                      (float*)d_out);
}

// Round 8
// 271.111 us; speedup vs baseline: 1.0290x; 1.0290x over previous
//
#include <hip/hip_runtime.h>

#define NN 100000
#define NP 100096          // multiple of 32/64
#define NT (NP / 32)       // 3128 gemm tiles
#define EE 600000
#define GG 512
#define LN_EPS 1e-5f

typedef __attribute__((ext_vector_type(8))) __bf16 bf16x8;
typedef __attribute__((ext_vector_type(4))) float f32x4;
typedef __attribute__((ext_vector_type(2))) float f32x2;

__device__ __forceinline__ unsigned short f2bf(float f) {
    unsigned int u = __float_as_uint(f);
    u = (u + 0x7fffu + ((u >> 16) & 1u)) >> 16;
    return (unsigned short)u;
}
__device__ __forceinline__ unsigned int pack2(float a, float b) {
    return (unsigned int)f2bf(a) | ((unsigned int)f2bf(b) << 16);
}
// accumulate 8 fp8 (uint2) into s[8] via HW converts (gfx940+ fp8-conversion-insts)
__device__ __forceinline__ void accq8(float* s, uint2 v) {
    f32x2 p0 = __builtin_amdgcn_cvt_pk_f32_fp8(v.x, false);
    f32x2 p1 = __builtin_amdgcn_cvt_pk_f32_fp8(v.x, true);
    f32x2 p2 = __builtin_amdgcn_cvt_pk_f32_fp8(v.y, false);
    f32x2 p3 = __builtin_amdgcn_cvt_pk_f32_fp8(v.y, true);
    s[0] += p0[0]; s[1] += p0[1]; s[2] += p1[0]; s[3] += p1[1];
    s[4] += p2[0]; s[5] += p2[1]; s[6] += p3[0]; s[7] += p3[1];
}
__device__ __forceinline__ unsigned int pkq4(float a, float b, float c, float d) {
    int t = __builtin_amdgcn_cvt_pk_fp8_f32(a, b, 0, false);
    return (unsigned int)__builtin_amdgcn_cvt_pk_fp8_f32(c, d, t, true);
}

// ---------------- merged prep: H0r + H0q + weight prep + XCD-partitioned degree --------
#define PREP_A (NP * 10)
#define PREP_W0 (128 * 160)
#define PREP_W1 (128 * 256)
#define PREP_WF (50 * 256 + 50 * 50 + 50 * 10)   // transposed MLP weights (15800)
#define PREP_AB   (PREP_A / 256)                 // 3910 blocks
#define PREP_W0B  (PREP_W0 / 256)                // 80
#define PREP_W1B  (PREP_W1 / 256)                // 128
#define PREP_WFB  ((PREP_WF + 255) / 256)        // 62 blocks (padded)
#define PREP_FIXED_B (PREP_AB + PREP_W0B + PREP_W1B + PREP_WFB)
#define ECHUNK 2048
#define NCHUNK ((EE + ECHUNK - 1) / ECHUNK)      // 293
#define PREP_GRID (PREP_FIXED_B + NCHUNK * 8)
#define PART 12500                               // 8*12500 = 100000 = NN

__global__ __launch_bounds__(256) void prep_kernel(
    const float* __restrict__ x, const float* __restrict__ xdims,
    const int* __restrict__ stt, const float* __restrict__ emb,
    const int* __restrict__ ei,
    const float* __restrict__ Wl0, const float* __restrict__ Wr0,
    const float* __restrict__ Wl1, const float* __restrict__ Wr1,
    const float* __restrict__ Wf0, const float* __restrict__ Wf1,
    const float* __restrict__ Wf2,
    unsigned short* __restrict__ H0r, unsigned char* __restrict__ H0q,
    unsigned short* __restrict__ Wt0, unsigned short* __restrict__ Wt1,
    float* __restrict__ W0T, float* __restrict__ W1T, float* __restrict__ W2T,
    int* __restrict__ deg)
{
    int blk = blockIdx.x;
    if (blk >= PREP_FIXED_B) {
        // ---- XCD-partitioned degree count ----
        int eb = blk - PREP_FIXED_B;
        int px = eb & 7, c = eb >> 3;
        int lo = px * PART, hi = lo + PART;
        int base = c * ECHUNK + threadIdx.x * 8;
        int d[8]; int n = 0;
        if (base + 8 <= EE) {
            int4 a = *(const int4*)&ei[EE + base];
            int4 b = *(const int4*)&ei[EE + base + 4];
            d[0]=a.x; d[1]=a.y; d[2]=a.z; d[3]=a.w;
            d[4]=b.x; d[5]=b.y; d[6]=b.z; d[7]=b.w;
            n = 8;
        } else {
            for (int u = 0; u < 8 && base + u < EE; ++u) d[u] = ei[EE + base + u];
            n = (base < EE) ? (EE - base < 8 ? EE - base : 8) : 0;
        }
        for (int u = 0; u < n; ++u)
            if (d[u] >= lo && d[u] < hi) atomicAdd(&deg[d[u]], 1);
        return;
    }
    int idx = blk * 256 + threadIdx.x;
    if (idx < PREP_A) {
        int node = idx / 10;
        int c8 = (idx - node * 10) * 8;   // feature base 0..72
        float fv[8];
        if (node < NN) {
            int st = stt[node];
            #pragma unroll
            for (int i = 0; i < 8; ++i) {
                int f = c8 + i;
                float v = 0.f;
                if (f < 60)      v = x[node * 60 + f];
                else if (f < 62) v = xdims[node * 2 + (f - 60)];
                else if (f < 74) v = emb[st * 12 + (f - 62)];
                fv[i] = v;
            }
        } else {
            #pragma unroll
            for (int i = 0; i < 8; ++i) fv[i] = 0.f;
        }
        uint4 o;
        o.x = pack2(fv[0], fv[1]);
        o.y = pack2(fv[2], fv[3]);
        o.z = pack2(fv[4], fv[5]);
        o.w = pack2(fv[6], fv[7]);
        *(uint4*)(H0r + (size_t)node * 80 + c8) = o;
        uint2 q;
        q.x = pkq4(fv[0], fv[1], fv[2], fv[3]);
        q.y = pkq4(fv[4], fv[5], fv[6], fv[7]);
        *(uint2*)(H0q + (size_t)node * 80 + c8) = q;
    } else if (idx < PREP_A + PREP_W0) {
        int j = idx - PREP_A;
        int n = j / 160, k = j - n * 160;
        float v = 0.f;
        if (k < 74)                  v = Wl0[k * 128 + n];
        else if (k >= 80 && k < 154) v = Wr0[(k - 80) * 128 + n];
        Wt0[(size_t)n * 160 + k] = f2bf(v);
    } else if (idx < PREP_A + PREP_W0 + PREP_W1) {
        int j = idx - PREP_A - PREP_W0;
        int n = j >> 8, k = j & 255;
        float v = (k < 128) ? Wl1[k * 128 + n] : Wr1[(k - 128) * 128 + n];
        Wt1[(size_t)n * 256 + k] = f2bf(v);
    } else {
        int j = idx - PREP_A - PREP_W0 - PREP_W1;
        if (j < 50 * 256) {
            int t = j >> 8, k = j & 255;
            W0T[t * 256 + k] = Wf0[k * 50 + t];
        } else if (j < 50 * 256 + 50 * 50) {
            int q = j - 50 * 256; int t = q / 50, k = q - t * 50;
            W1T[t * 50 + k] = Wf1[k * 50 + t];
        } else if (j < PREP_WF) {
            int q = j - 50 * 256 - 50 * 50; int t = q / 50, k = q - t * 50;
            W2T[t * 50 + k] = Wf2[k * 10 + t];
        }
    }
}

// ---------------- exclusive scan of deg -> offs (local) + bsum ----------------
__global__ __launch_bounds__(256) void scan1_kernel(
    const int* __restrict__ deg, int* __restrict__ offs, int* __restrict__ bsum)
{
    __shared__ int ts[256];
    int t = threadIdx.x;
    int base = blockIdx.x * 2048 + t * 8;
    int d[8];
    if (base + 8 <= NN) {
        int4 a = *(const int4*)&deg[base];
        int4 b = *(const int4*)&deg[base + 4];
        d[0]=a.x; d[1]=a.y; d[2]=a.z; d[3]=a.w;
        d[4]=b.x; d[5]=b.y; d[6]=b.z; d[7]=b.w;
    } else {
        #pragma unroll
        for (int i = 0; i < 8; ++i) d[i] = (base + i < NN) ? deg[base + i] : 0;
    }
    int e[8]; int run = 0;
    #pragma unroll
    for (int i = 0; i < 8; ++i) { e[i] = run; run += d[i]; }
    ts[t] = run;
    int tot = run;
    __syncthreads();
    for (int off = 1; off < 256; off <<= 1) {
        int u = (t >= off) ? ts[t - off] : 0;
        __syncthreads();
        ts[t] += u;
        __syncthreads();
    }
    int pre = ts[t] - tot;
    #pragma unroll
    for (int i = 0; i < 8; ++i) if (base + i < NN) offs[base + i] = e[i] + pre;
    if (t == 255) bsum[blockIdx.x] = ts[255];
}

__global__ void scan2_kernel(int* __restrict__ bsum, int nb)
{
    int t = threadIdx.x;   // one wave
    int v = (t < nb) ? bsum[t] : 0;
    int inc = v;
    for (int off = 1; off < 64; off <<= 1) {
        int u = __shfl_up(inc, off, 64);
        if (t >= off) inc += u;
    }
    if (t < nb) bsum[t] = inc - v;   // exclusive
}

// ---------------- CSR fill, XCD-partitioned ----------------
__global__ __launch_bounds__(256) void fill_csr_kernel(
    const int* __restrict__ ei, int* __restrict__ cur,
    const int* __restrict__ offs, const int* __restrict__ bsum,
    int* __restrict__ csr)
{
    int px = blockIdx.x & 7, c = blockIdx.x >> 3;
    int lo = px * PART, hi = lo + PART;
    int base = c * ECHUNK + threadIdx.x * 8;
    int d[8]; int n = 0;
    if (base + 8 <= EE) {
        int4 a = *(const int4*)&ei[EE + base];
        int4 b = *(const int4*)&ei[EE + base + 4];
        d[0]=a.x; d[1]=a.y; d[2]=a.z; d[3]=a.w;
        d[4]=b.x; d[5]=b.y; d[6]=b.z; d[7]=b.w;
        n = 8;
    } else {
        for (int u = 0; u < 8 && base + u < EE; ++u) d[u] = ei[EE + base + u];
        n = (base < EE) ? (EE - base < 8 ? EE - base : 8) : 0;
    }
    for (int u = 0; u < n; ++u) {
        int dd = d[u];
        if (dd >= lo && dd < hi) {
            int p = offs[dd] + bsum[dd >> 11] + atomicAdd(&cur[dd], 1);
            csr[p] = ei[base + u];
        }
    }
}

// ---------------- fused gather-agg + GEMM (+ LN + ReLU; POOL: + pooling) ----------
// R8: gather reads fp8-e4m3 shadow rows (Hq, K/2 bytes/row) -> halves the
// random-line count that hits the HBM random-access wall (the invariant
// FETCH/dur = 1.34 TB/s across R1/R3/R4/R5/R7). Root rows + weights + MFMA
// stay bf16 (exact). HW converts: accq8 is cheaper than the bf16 unpack.
// !POOL additionally emits outHq (fp8 H1) via an LDS re-pack phase.
// block = 256 thr = 4 waves; 32 nodes x 128 cols; A in LDS stride AS=K+8.
// Ledger: regB-resident, persistent, direct-global A-frags, async
// global_load_lds, 64-node tile, 2-tile dbuf, 8-wide clamped gather (R1),
// 8-wave/512-thr (R4), XCD atomic partition (R7: null) vs this form.
template<int K, bool POOL>
__global__ __launch_bounds__(256, 4) void gemm_kernel(
    const unsigned short* __restrict__ Hr,        // root source (bf16, K/2 cols)
    const unsigned char* __restrict__ Hq,         // gather source (fp8, K/2 cols)
    const unsigned short* __restrict__ Wt,
    const float* __restrict__ bias, const float* __restrict__ gamma,
    const float* __restrict__ beta,
    unsigned short* __restrict__ outH,            // !POOL: H1 (bf16 dense 128)
    unsigned char* __restrict__ outHq,            // !POOL: H1q (fp8 dense 128)
    const int* __restrict__ batch,                // POOL only
    float* __restrict__ psum, int* __restrict__ pmax, int* __restrict__ gcnt,
    const int* __restrict__ csr, const int* __restrict__ offs,
    const int* __restrict__ bsum, const int* __restrict__ deg)
{
    constexpr int KT = K / 32, AS = K + 8, KH = K / 2, CH = KH / 8;
    constexpr int SMEM = (32 * AS * 2 > 32 * 128 * 4) ? 32 * AS * 2 : 32 * 128 * 4;
    __shared__ __align__(16) char smem[SMEM];     // Asm; aliased by Hs post-MFMA
    unsigned short* Asm = (unsigned short*)smem;
    float* Hs = (float*)smem;
    __shared__ __align__(16) float sP[32 * 4];
    __shared__ __align__(16) float qP[32 * 4];
    __shared__ int bS[POOL ? 32 : 1];

    const int tid = threadIdx.x;
    const int n0 = blockIdx.x * 32;
    const int l = tid & 63, w = tid >> 6;
    const int fg = l >> 4, c0 = l & 15;

    if (POOL && tid < 32) {
        int gn = n0 + tid;
        bS[tid] = (gn < NN) ? batch[gn] : -1;
    }
    float bia[2], gam[2], bet[2];
    #pragma unroll
    for (int j = 0; j < 2; ++j) {
        int col = (2 * w + j) * 16 + c0;
        bia[j] = bias[col]; gam[j] = gamma[col]; bet[j] = beta[col];
    }
    const unsigned short* bp0 = Wt + (size_t)((2 * w + 0) * 16 + c0) * K + fg * 8;
    const unsigned short* bp1 = Wt + (size_t)((2 * w + 1) * 16 + c0) * K + fg * 8;

    // ---- fused staging: Asm row = [fp8-gather neighbor-mean (KH) | bf16 root (KH)] ----
    {
        const int ln = tid & 15, nl = tid >> 4;   // 16 lanes per node, 16 nodes/pass
        #pragma unroll
        for (int half = 0; half < 2; ++half) {
            int node = half * 16 + nl;
            int gn = n0 + node;
            if (ln < CH) {
                uint4 rv = *(const uint4*)(Hr + (size_t)gn * KH + ln * 8);
                int d = 0, st = 0;
                if (gn < NN) { d = deg[gn]; st = offs[gn] + bsum[gn >> 11]; }
                float iv = 1.0f / (float)(d > 1 ? d : 1);
                float s[8];
                #pragma unroll
                for (int i = 0; i < 8; ++i) s[i] = 0.f;
                int e = 0;
                for (; e + 4 <= d; e += 4) {
                    int i0 = csr[st + e],     i1 = csr[st + e + 1];
                    int i2 = csr[st + e + 2], i3 = csr[st + e + 3];
                    uint2 v0 = *(const uint2*)(Hq + (size_t)i0 * KH + ln * 8);
                    uint2 v1 = *(const uint2*)(Hq + (size_t)i1 * KH + ln * 8);
                    uint2 v2 = *(const uint2*)(Hq + (size_t)i2 * KH + ln * 8);
                    uint2 v3 = *(const uint2*)(Hq + (size_t)i3 * KH + ln * 8);
                    accq8(s, v0); accq8(s, v1); accq8(s, v2); accq8(s, v3);
                }
                for (; e < d; ++e) {
                    int i0 = csr[st + e];
                    uint2 v0 = *(const uint2*)(Hq + (size_t)i0 * KH + ln * 8);
                    accq8(s, v0);
                }
                uint4 o;
                o.x = pack2(s[0] * iv, s[1] * iv);
                o.y = pack2(s[2] * iv, s[3] * iv);
                o.z = pack2(s[4] * iv, s[5] * iv);
                o.w = pack2(s[6] * iv, s[7] * iv);
                *(uint4*)(Asm + node * AS + ln * 8) = o;            // agg half
                *(uint4*)(Asm + node * AS + KH + ln * 8) = rv;      // root half
            }
        }
    }

    const unsigned short* ar0 = Asm + (0 * 16 + c0) * AS + fg * 8;
    const unsigned short* ar1 = Asm + (1 * 16 + c0) * AS + fg * 8;
    __syncthreads();

    f32x4 acc[2][2];
    acc[0][0] = (f32x4){0.f,0.f,0.f,0.f}; acc[0][1] = (f32x4){0.f,0.f,0.f,0.f};
    acc[1][0] = (f32x4){0.f,0.f,0.f,0.f}; acc[1][1] = (f32x4){0.f,0.f,0.f,0.f};

    #pragma unroll
    for (int kt = 0; kt < KT; ++kt) {
        bf16x8 b0 = *(const bf16x8*)(bp0 + kt * 32);
        bf16x8 b1 = *(const bf16x8*)(bp1 + kt * 32);
        bf16x8 a0 = *(const bf16x8*)(ar0 + kt * 32);
        bf16x8 a1 = *(const bf16x8*)(ar1 + kt * 32);
        acc[0][0] = __builtin_amdgcn_mfma_f32_16x16x32_bf16(a0, b0, acc[0][0], 0, 0, 0);
        acc[0][1] = __builtin_amdgcn_mfma_f32_16x16x32_bf16(a0, b1, acc[0][1], 0, 0, 0);
        acc[1][0] = __builtin_amdgcn_mfma_f32_16x16x32_bf16(a1, b0, acc[1][0], 0, 0, 0);
        acc[1][1] = __builtin_amdgcn_mfma_f32_16x16x32_bf16(a1, b1, acc[1][1], 0, 0, 0);
    }

    // LN phase 1: per-wave partials over this wave's 32 cols
    #pragma unroll
    for (int m = 0; m < 2; ++m) {
        #pragma unroll
        for (int r = 0; r < 4; ++r) {
            float h0v = acc[m][0][r] + bia[0];
            float h1v = acc[m][1][r] + bia[1];
            float s = h0v + h1v, q = h0v * h0v + h1v * h1v;
            #pragma unroll
            for (int mm = 1; mm < 16; mm <<= 1) {
                s += __shfl_xor(s, mm, 64);
                q += __shfl_xor(q, mm, 64);
            }
            if (c0 == 0) {
                int node = m * 16 + fg * 4 + r;
                sP[node * 4 + w] = s;
                qP[node * 4 + w] = q;
            }
        }
    }
    __syncthreads();   // MFMA Asm reads done; sP/qP visible

    // LN phase 2 + ReLU + store (POOL: f32 to Hs; !POOL: bf16 direct + Hs for fp8 pack)
    #pragma unroll
    for (int m = 0; m < 2; ++m) {
        #pragma unroll
        for (int r = 0; r < 4; ++r) {
            int node = m * 16 + fg * 4 + r;
            float4 sv = *(const float4*)&sP[node * 4];
            float4 qv = *(const float4*)&qP[node * 4];
            float s = (sv.x + sv.y) + (sv.z + sv.w);
            float q = (qv.x + qv.y) + (qv.z + qv.w);
            float mu   = s * (1.f / 128.f);
            float var  = q * (1.f / 128.f) - mu * mu;
            float rinv = rsqrtf(var + LN_EPS);
            float h0v = acc[m][0][r] + bia[0];
            float h1v = acc[m][1][r] + bia[1];
            float v0 = fmaxf(0.f, (h0v - mu) * rinv * gam[0] + bet[0]);
            float v1 = fmaxf(0.f, (h1v - mu) * rinv * gam[1] + bet[1]);
            if (POOL) {
                Hs[node * 128 + (2 * w) * 16 + c0]     = v0;
                Hs[node * 128 + (2 * w + 1) * 16 + c0] = v1;
            } else {
                size_t gn = (size_t)(n0 + node);
                float keep = (gn < (size_t)NN) ? 1.f : 0.f;
                float v0k = v0 * keep, v1k = v1 * keep;
                Hs[node * 128 + (2 * w) * 16 + c0]     = v0k;
                Hs[node * 128 + (2 * w + 1) * 16 + c0] = v1k;
                outH[gn * 128 + (2 * w) * 16 + c0]     = f2bf(v0k);
                outH[gn * 128 + (2 * w + 1) * 16 + c0] = f2bf(v1k);
            }
        }
    }
    __syncthreads();

    if (!POOL) {
        // fp8 re-pack: 256 threads, one (node, 16-col chunk) each
        int node = tid >> 3, ch = tid & 7;
        size_t gn = (size_t)(n0 + node);
        const float* hrow = Hs + node * 128 + ch * 16;
        uint4 q;
        q.x = pkq4(hrow[0],  hrow[1],  hrow[2],  hrow[3]);
        q.y = pkq4(hrow[4],  hrow[5],  hrow[6],  hrow[7]);
        q.z = pkq4(hrow[8],  hrow[9],  hrow[10], hrow[11]);
        q.w = pkq4(hrow[12], hrow[13], hrow[14], hrow[15]);
        *(uint4*)(outHq + gn * 128 + ch * 16) = q;
        return;
    }

    // fused pooling: 128 threads, one column each; sorted batch -> few flushes.
    // Thread j==0 also accumulates per-graph node counts.
    if (tid < 128) {
        int j = tid;
        int curg = -1; float s = 0.f, m = 0.f; int rl = 0;
        #pragma unroll 4
        for (int n = 0; n < 32; ++n) {
            int gb = bS[n];
            if (gb < 0) break;
            if (gb != curg) {
                if (curg >= 0) {
                    atomicAdd(&psum[curg * 128 + j], s);
                    atomicMax(&pmax[curg * 128 + j], __float_as_int(m));
                    if (j == 0) atomicAdd(&gcnt[curg], rl);
                }
                curg = gb; s = 0.f; m = 0.f; rl = 0;
            }
            float v = Hs[n * 128 + j];
            s += v; m = fmaxf(m, v);
            rl += 1;
        }
        if (curg >= 0) {
            atomicAdd(&psum[curg * 128 + j], s);
            atomicMax(&pmax[curg * 128 + j], __float_as_int(m));
            if (j == 0) atomicAdd(&gcnt[curg], rl);
        }
    }
}

// ---------------- final MLP (transposed weights: thread t streams a contiguous row) ----
__global__ __launch_bounds__(64) void mlp_kernel(
    const float* __restrict__ psum, const int* __restrict__ pmax,
    const int* __restrict__ gcnt,
    const float* __restrict__ W0T, const float* __restrict__ bf0,
    const float* __restrict__ W1T, const float* __restrict__ bf1,
    const float* __restrict__ W2T, const float* __restrict__ bf2,
    float* __restrict__ out)
{
    __shared__ float z[256];
    __shared__ float t1[50];
    __shared__ float t2[50];
    int g = blockIdx.x, t = threadIdx.x;
    int c = gcnt[g];
    float ic = 1.0f / (float)(c > 1 ? c : 1);
    for (int j = t; j < 128; j += 64) {
        z[j]       = psum[g * 128 + j] * ic;
        z[128 + j] = __int_as_float(pmax[g * 128 + j]);
    }
    __syncthreads();
    if (t < 50) {
        const float* wr = W0T + t * 256;
        float a0 = bf0[t], a1 = 0.f, a2 = 0.f, a3 = 0.f;
        for (int k = 0; k < 256; k += 4) {
            float4 wv = *(const float4*)(wr + k);
            a0 = fmaf(z[k],     wv.x, a0);
            a1 = fmaf(z[k + 1], wv.y, a1);
            a2 = fmaf(z[k + 2], wv.z, a2);
            a3 = fmaf(z[k + 3], wv.w, a3);
        }
        t1[t] = fmaxf((a0 + a1) + (a2 + a3), 0.0f);
    }
    __syncthreads();
    if (t < 50) {
        const float* wr = W1T + t * 50;
        float a0 = bf1[t], a1 = 0.f;
        for (int k = 0; k < 50; k += 2) {
            a0 = fmaf(t1[k],     wr[k],     a0);
            a1 = fmaf(t1[k + 1], wr[k + 1], a1);
        }
        t2[t] = fmaxf(a0 + a1, 0.0f);
    }
    __syncthreads();
    if (t < 10) {
        const float* wr = W2T + t * 50;
        float a0 = bf2[t], a1 = 0.f;
        for (int k = 0; k < 50; k += 2) {
            a0 = fmaf(t2[k],     wr[k],     a0);
            a1 = fmaf(t2[k + 1], wr[k + 1], a1);
        }
        out[g * 10 + t] = fmaxf(a0 + a1, 0.0f);
    }
}

// ---------------- launcher ----------------
extern "C" void kernel_launch(void* const* d_in, const int* in_sizes, int n_in,
                              void* d_out, int out_size, void* d_ws, size_t ws_size,
                              hipStream_t stream)
{
    const float* x     = (const float*)d_in[0];
    const float* xdims = (const float*)d_in[1];
    const int*   stt   = (const int*)d_in[2];
    const int*   ei    = (const int*)d_in[3];
    const int*   batch = (const int*)d_in[4];
    const float* emb   = (const float*)d_in[5];
    const float* Wl0   = (const float*)d_in[6];
    const float* bl0   = (const float*)d_in[7];
    const float* Wr0   = (const float*)d_in[8];
    const float* g0    = (const float*)d_in[9];
    const float* bn0   = (const float*)d_in[10];
    const float* Wl1   = (const float*)d_in[11];
    const float* bl1   = (const float*)d_in[12];
    const float* Wr1   = (const float*)d_in[13];
    const float* g1    = (const float*)d_in[14];
    const float* bn1   = (const float*)d_in[15];
    const float* Wf0   = (const float*)d_in[16];
    const float* bf0   = (const float*)d_in[17];
    const float* Wf1   = (const float*)d_in[18];
    const float* bf1   = (const float*)d_in[19];
    const float* Wf2   = (const float*)d_in[20];
    const float* bf2   = (const float*)d_in[21];

    char* w = (char*)d_ws;
    unsigned short* H0r = (unsigned short*)w; w += (size_t)NP * 80 * 2;
    unsigned short* H1  = (unsigned short*)w; w += (size_t)NP * 128 * 2;
    unsigned char*  H0q = (unsigned char*)w;  w += (size_t)NP * 80;
    unsigned char*  H1q = (unsigned char*)w;  w += (size_t)NP * 128;
    unsigned short* Wt0 = (unsigned short*)w; w += (size_t)128 * 160 * 2;
    unsigned short* Wt1 = (unsigned short*)w; w += (size_t)128 * 256 * 2;
    float* W0T = (float*)w; w += (size_t)50 * 256 * 4;
    float* W1T = (float*)w; w += (size_t)50 * 50 * 4;
    float* W2T = (float*)w; w += (size_t)10 * 50 * 4;
    int*   csr    = (int*)w;   w += (size_t)EE * 4;
    int*   offs   = (int*)w;   w += (size_t)NN * 4;
    int*   bsum   = (int*)w;   w += 1024;
    // zeroed region (one memset):
    char* zbeg = w;
    int*   deg  = (int*)w;   w += (size_t)NP * 4;
    int*   cur  = (int*)w;   w += (size_t)NN * 4;
    float* psum = (float*)w; w += (size_t)GG * 128 * 4;
    int*   pmax = (int*)w;   w += (size_t)GG * 128 * 4;
    int*   gcnt = (int*)w;   w += (size_t)GG * 4;
    size_t zsz = (size_t)(w - zbeg);

    hipMemsetAsync(zbeg, 0, zsz, stream);

    prep_kernel<<<PREP_GRID, 256, 0, stream>>>(
        x, xdims, stt, emb, ei, Wl0, Wr0, Wl1, Wr1, Wf0, Wf1, Wf2,
        H0r, H0q, Wt0, Wt1, W0T, W1T, W2T, deg);

    int nb = (NN + 2047) / 2048;   // 49
    scan1_kernel<<<nb, 256, 0, stream>>>(deg, offs, bsum);
    scan2_kernel<<<1, 64, 0, stream>>>(bsum, nb);
    fill_csr_kernel<<<NCHUNK * 8, 256, 0, stream>>>(ei, cur, offs, bsum, csr);

    gemm_kernel<160, false><<<NT, 256, 0, stream>>>(
        H0r, H0q, Wt0, bl0, g0, bn0, H1, H1q, nullptr, nullptr, nullptr, nullptr,
        csr, offs, bsum, deg);
    gemm_kernel<256, true><<<NT, 256, 0, stream>>>(
        H1, H1q, Wt1, bl1, g1, bn1, nullptr, nullptr, batch, psum, pmax, gcnt,
        csr, offs, bsum, deg);

    mlp_kernel<<<GG, 64, 0, stream>>>(psum, pmax, gcnt, W0T, bf0, W1T, bf1, W2T, bf2,
                                      (float*)d_out);
}